// Round 16
// baseline (164.129 us; speedup 1.0000x reference)
//
#include <hip/hip_runtime.h>

typedef _Float16 f16;
typedef f16 f16x4 __attribute__((ext_vector_type(4)));
typedef f16 f16x8 __attribute__((ext_vector_type(8)));
typedef float f32x4 __attribute__((ext_vector_type(4)));

#define LSCALE 2048.0f          // lo-parts stored *2^11 (exact) to avoid f16 denormals
#define LINV   4.8828125e-4f    // 2^-11
#define XSX 136                 // X planes stride (halfs): b128-aligned rows, conflict-free reads
#define XSW 140                 // W planes stride (halfs): rows+4k -> banks {0,24,16,8}, conflict-free

#define MFMA(A,B,C) __builtin_amdgcn_mfma_f32_16x16x32_f16(A, B, C, 0, 0, 0)

// ---------------------------------------------------------------------------
// Kernel 0: replicate the reference's fp32 cas table EXACTLY (round-2 lesson:
// a more accurate table FAILS), then write split-f16 tables A=cas and
// V[f][m]=cas[f][127-m] in MFMA-FRAGMENT ORDER (round-10 lesson: row-major
// fragment loads are 32-line gathers; frag order -> one coalesced transaction).
// ---------------------------------------------------------------------------
__device__ __forceinline__ int frag_slot(int row, int k) {
    return ((((row >> 4) * 4 + (k >> 5)) * 64) + ((k >> 3) & 3) * 16 + (row & 15)) * 8 + (k & 7);
}

__global__ void k_cas(float* __restrict__ casf,
                      f16* __restrict__ FAh, f16* __restrict__ FAl,
                      f16* __restrict__ FVh, f16* __restrict__ FVl) {
    int f = blockIdx.x, m = threadIdx.x;
    const float SC = (float)(6.283185307179586 / 128.0);  // fp32(2*pi/128)
    float ang = SC * (float)(f * m);                      // fp32, unreduced
    double a = (double)ang;
    float v = (float)cos(a) + (float)sin(a);
    casf[f * 128 + m] = v;
    f16 h = (f16)v;
    f16 lo = (f16)((v - (float)h) * LSCALE);
    int sA = frag_slot(f, m);
    FAh[sA] = h;
    FAl[sA] = lo;
    int sV = frag_slot(f, 127 - m);    // V[f][127-m] = cas[f][m]
    FVh[sV] = h;
    FVl[sV] = lo;
}

// ---------------------------------------------------------------------------
// Kernel 1: round-15 structure (2 blocks/image by g-half, 71.7KB LDS,
// 2 blocks/CU) + NEW: also scatter negation-permuted corner copies cp1n/cp2n
// (pn(f,g) = ((16-f)&15, (16-g)&15), block-local) so k_inv's corner reads
// are aligned float4. Math chain unchanged -> bitwise-identical C/S.
// ---------------------------------------------------------------------------
__global__ __launch_bounds__(512, 2) void k_dht(
    const float* __restrict__ xg,
    const f16* __restrict__ FAh, const f16* __restrict__ FAl,
    const f16* __restrict__ FVh, const f16* __restrict__ FVl,
    float* __restrict__ outbuf,
    float* __restrict__ cp1, float* __restrict__ cp2,
    float* __restrict__ cp1n, float* __restrict__ cp2n)
{
    __shared__ __align__(16) char smem[71680];
    f16* Xh  = (f16*)smem;               // [128][XSX] = 34816 B
    f16* Xl  = (f16*)(smem + 34816);     // ends 69632
    f16* W1h = (f16*)smem;               // [64][XSW] = 17920 B each, overlay X after pass 1
    f16* W1l = (f16*)(smem + 17920);
    f16* W2h = (f16*)(smem + 35840);
    f16* W2l = (f16*)(smem + 53760);     // ends 71680

    const int img = blockIdx.x;
    const int gh  = blockIdx.y;          // g-half: 0 or 1
    const float* X = xg + (size_t)img * 16384;
    const int t = threadIdx.x;           // 0..511
    const int lane = t & 63;
    const int wv = t >> 6;               // 0..7
    const int l15 = lane & 15;
    const int a4 = lane >> 4;            // 0..3

    // ---- stage X -> split fp16 planes in LDS (b64 vector writes) ----
    #pragma unroll
    for (int it = 0; it < 8; ++it) {
        int i = it * 512 + t;            // float4 index 0..4095
        int r = i >> 5, c0 = (i & 31) * 4;
        float4 xv = *(const float4*)&X[r * 128 + c0];
        const float* xp = (const float*)&xv;
        f16x4 hv, lv;
        #pragma unroll
        for (int j = 0; j < 4; ++j) {
            f16 h = (f16)xp[j];
            hv[j] = h;
            lv[j] = (f16)((xp[j] - (float)h) * LSCALE);
        }
        *(f16x4*)&Xh[r * XSX + c0] = hv;
        *(f16x4*)&Xl[r * XSX + c0] = lv;
    }
    __syncthreads();

    // ---- pass 1: wave tile (g local [32gq,+32), m [32mq,+32)) ----
    const int gq = wv >> 2, mq = wv & 3;     // gq 0..1, mq 0..3
    const int Gq = 2 * gh + gq;              // global 32-row g-tile 0..3
    f32x4 w1hi[2][2], w1lo[2][2], w2hi[2][2], w2lo[2][2];
    #pragma unroll
    for (int i = 0; i < 2; ++i)
        #pragma unroll
        for (int j = 0; j < 2; ++j) {
            w1hi[i][j] = (f32x4){0.f,0.f,0.f,0.f}; w1lo[i][j] = (f32x4){0.f,0.f,0.f,0.f};
            w2hi[i][j] = (f32x4){0.f,0.f,0.f,0.f}; w2lo[i][j] = (f32x4){0.f,0.f,0.f,0.f};
        }
    {
        #pragma unroll 1
        for (int ks = 0; ks < 4; ++ks) {
            f16x8 tah[2], tal[2], tvh[2], tvl[2];
            #pragma unroll
            for (int gt = 0; gt < 2; ++gt) {
                const int toff = (((2 * Gq + gt) * 4 + ks) * 64 + lane) * 8;
                tah[gt] = *(const f16x8*)&FAh[toff];
                tal[gt] = *(const f16x8*)&FAl[toff];
                tvh[gt] = *(const f16x8*)&FVh[toff];
                tvl[gt] = *(const f16x8*)&FVl[toff];
            }
            #pragma unroll
            for (int mt = 0; mt < 2; ++mt) {
                const int base = (32 * mq + 16 * mt + l15) * XSX + ks * 32 + 8 * a4;
                f16x8 xh = *(const f16x8*)&Xh[base];            // aligned b128
                f16x8 xl = *(const f16x8*)&Xl[base];
                #pragma unroll
                for (int gt = 0; gt < 2; ++gt) {
                    w1hi[gt][mt] = MFMA(tah[gt], xh, w1hi[gt][mt]);
                    w1lo[gt][mt] = MFMA(tal[gt], xh, w1lo[gt][mt]);
                    w1lo[gt][mt] = MFMA(tah[gt], xl, w1lo[gt][mt]);
                    w2hi[gt][mt] = MFMA(tvh[gt], xh, w2hi[gt][mt]);
                    w2lo[gt][mt] = MFMA(tvl[gt], xh, w2lo[gt][mt]);
                    w2lo[gt][mt] = MFMA(tvh[gt], xl, w2lo[gt][mt]);
                }
            }
        }
    }
    __syncthreads();   // X reads done before W overwrites the X region

    // ---- combine + split W into f16 h/l planes (local g rows 0..63) ----
    {
        #pragma unroll
        for (int gt = 0; gt < 2; ++gt)
            #pragma unroll
            for (int mt = 0; mt < 2; ++mt) {
                const int m = 32 * mq + 16 * mt + l15;
                #pragma unroll
                for (int r = 0; r < 4; ++r) {
                    const int g = 32 * gq + 16 * gt + 4 * a4 + r;   // local
                    float v1 = w1hi[gt][mt][r] + LINV * w1lo[gt][mt][r];
                    f16 h1 = (f16)v1;
                    float v2 = w2hi[gt][mt][r] + LINV * w2lo[gt][mt][r];
                    f16 h2 = (f16)v2;
                    W2h[g * XSW + m] = h2;
                    W2l[g * XSW + m] = (f16)((v2 - (float)h2) * LSCALE);
                    W1h[g * XSW + m] = h1;
                    W1l[g * XSW + m] = (f16)((v1 - (float)h1) * LSCALE);
                }
            }
    }
    __syncthreads();

    // ---- pass 2: wave tile (f [32fq,+32), g local [32gq2,+32)) ----
    const int fq = wv >> 1, gq2 = wv & 1;    // fq 0..3, gq2 0..1
    f32x4 chi[2][2], clo[2][2], shi[2][2], slo[2][2];
    #pragma unroll
    for (int i = 0; i < 2; ++i)
        #pragma unroll
        for (int j = 0; j < 2; ++j) {
            chi[i][j] = (f32x4){0.f,0.f,0.f,0.f}; clo[i][j] = (f32x4){0.f,0.f,0.f,0.f};
            shi[i][j] = (f32x4){0.f,0.f,0.f,0.f}; slo[i][j] = (f32x4){0.f,0.f,0.f,0.f};
        }
    {
        #pragma unroll 1
        for (int ks = 0; ks < 4; ++ks) {
            f16x8 tah[2], tal[2], tvh[2], tvl[2];
            #pragma unroll
            for (int ft = 0; ft < 2; ++ft) {
                const int toff = (((2 * fq + ft) * 4 + ks) * 64 + lane) * 8;
                tah[ft] = *(const f16x8*)&FAh[toff];
                tal[ft] = *(const f16x8*)&FAl[toff];
                tvh[ft] = *(const f16x8*)&FVh[toff];
                tvl[ft] = *(const f16x8*)&FVl[toff];
            }
            #pragma unroll
            for (int gt = 0; gt < 2; ++gt) {
                const int wb = (32 * gq2 + 16 * gt + l15) * XSW + ks * 32 + 8 * a4;
                f16x4 a0 = *(const f16x4*)&W1h[wb];
                f16x4 a1 = *(const f16x4*)&W1h[wb + 4];
                f16x4 b0 = *(const f16x4*)&W1l[wb];
                f16x4 b1 = *(const f16x4*)&W1l[wb + 4];
                f16x4 c0 = *(const f16x4*)&W2h[wb];
                f16x4 c1 = *(const f16x4*)&W2h[wb + 4];
                f16x4 d0 = *(const f16x4*)&W2l[wb];
                f16x4 d1 = *(const f16x4*)&W2l[wb + 4];
                f16x8 u1h = __builtin_shufflevector(a0, a1, 0,1,2,3,4,5,6,7);
                f16x8 u1l = __builtin_shufflevector(b0, b1, 0,1,2,3,4,5,6,7);
                f16x8 u2h = __builtin_shufflevector(c0, c1, 0,1,2,3,4,5,6,7);
                f16x8 u2l = __builtin_shufflevector(d0, d1, 0,1,2,3,4,5,6,7);
                #pragma unroll
                for (int ft = 0; ft < 2; ++ft) {
                    chi[ft][gt] = MFMA(tah[ft], u1h, chi[ft][gt]);
                    clo[ft][gt] = MFMA(tal[ft], u1h, clo[ft][gt]);
                    clo[ft][gt] = MFMA(tah[ft], u1l, clo[ft][gt]);
                    shi[ft][gt] = MFMA(tvh[ft], u2h, shi[ft][gt]);
                    slo[ft][gt] = MFMA(tvl[ft], u2h, slo[ft][gt]);
                    slo[ft][gt] = MFMA(tvh[ft], u2l, slo[ft][gt]);
                }
            }
        }
    }

    // ---- epilogue: cosphi (f16, packed into out) + corners (+ negated copies) ----
    f16* cph = (f16*)(outbuf + (size_t)img * 16384);
    #pragma unroll
    for (int ft = 0; ft < 2; ++ft)
        #pragma unroll
        for (int gt = 0; gt < 2; ++gt) {
            const int g = 64 * gh + 32 * gq2 + 16 * gt + l15;    // global g
            #pragma unroll
            for (int r = 0; r < 4; ++r) {
                const int f = 32 * fq + 16 * ft + 4 * a4 + r;
                float Cv = chi[ft][gt][r] + LINV * clo[ft][gt][r];
                float Sv = shi[ft][gt][r] + LINV * slo[ft][gt][r];
                float d = Cv * Cv + Sv * Sv;
                float cp = (d > 0.f) ? Cv * rsqrtf(d) : 1.0f;
                cph[f * 128 + g] = (f16)cp;
                if (gh == 0 && gq2 == 0 && gt == 0) {    // g = l15 in 0..15
                    const int gn = (16 - l15) & 15;
                    if (fq == 0 && ft == 0) {            // f in 0..15
                        cp1[img * 256 + f * 16 + l15] = Cv;
                        cp1n[img * 256 + ((16 - f) & 15) * 16 + gn] = Cv;
                    } else if (fq == 3 && ft == 1) {     // f in 112..127
                        const int fl = f - 112;
                        cp2[img * 256 + fl * 16 + l15] = Cv;
                        cp2n[img * 256 + ((16 - fl) & 15) * 16 + gn] = Cv;
                    }
                }
            }
        }
}

// ---------------------------------------------------------------------------
// Kernel 2 (fused corner + sparse inverse + final multiply):
// NEW corner phase: waves 0-1 (128 threads) do the corner with FLOAT4 loads —
// thread owns (corner, x, 4 y's); An from the negated copies (aligned f4);
// Wn assembled from two aligned quads: lo=quad@(12-yb), up=quad@((16-yb)&15),
// Wn4 = {up.x, lo.w, lo.z, lo.y} (valid for all yb incl. the yb=0 wrap).
// Waves 2-3 concurrently stage casF/casG. Corner mem-instrs/block: 2048->640.
// R phase + final phase = round-13 (proven). cosphi preload at top (rule #20:
// fully unrolled, static indices -> VGPRs).
// ---------------------------------------------------------------------------
__global__ __launch_bounds__(256) void k_inv(
    const float* __restrict__ cp1, const float* __restrict__ cp2,
    const float* __restrict__ cp1n, const float* __restrict__ cp2n,
    const float* __restrict__ w1,  const float* __restrict__ w2,
    const float* __restrict__ cas,
    float* __restrict__ out)
{
    __shared__ float odS[32 * 16];
    __shared__ float casF[128 * 33];
    __shared__ float Rs[128 * 17];
    __shared__ float casG[16 * 128];

    const int img = blockIdx.x;
    const int b = img >> 6, o = img & 63;
    const int t = threadIdx.x;
    const int grp = t >> 5, lane = t & 31;
    const int s2 = lane * 4;

    // ---- issue cosphi preload EARLY (latency hides under corner phase) ----
    const f16* phg = (const f16*)(out + (size_t)img * 16384);
    f16x4 phv[16];
    #pragma unroll
    for (int r = 0; r < 16; ++r)
        phv[r] = *(const f16x4*)&phg[(grp * 16 + r) * 128 + s2];

    if (t < 128) {
        // ---- corner phase, float4, one corner + 4 pixels per thread ----
        const int c  = t >> 6;                // corner 0/1
        const int s  = t & 63;
        const int xx = s >> 2;
        const int yb = (s & 3) * 4;
        const int pix = xx * 16 + yb;
        const int nx = (16 - xx) & 15;
        const int nlo = nx * 16 + (12 - yb);          // aligned quad (low)
        const int nup = nx * 16 + ((16 - yb) & 15);   // aligned quad (high)
        const float* cp  = c ? cp2  : cp1;
        const float* cpn = c ? cp2n : cp1n;
        const float* w   = c ? w2   : w1;
        float4 accp = {0.f,0.f,0.f,0.f}, accm = {0.f,0.f,0.f,0.f};
        #pragma unroll 4
        for (int i = 0; i < 64; ++i) {
            const int cb = (b * 64 + i) * 256;
            const int wb = (i * 64 + o) * 256;
            float4 A4  = *(const float4*)&cp[cb + pix];
            float4 An4 = *(const float4*)&cpn[cb + pix];
            float4 W4  = *(const float4*)&w[wb + pix];
            float4 lo  = *(const float4*)&w[wb + nlo];
            float4 up  = *(const float4*)&w[wb + nup];
            float4 Wn4 = { up.x, lo.w, lo.z, lo.y };
            accp.x = fmaf(A4.x,  W4.x + Wn4.x, accp.x);
            accm.x = fmaf(An4.x, W4.x - Wn4.x, accm.x);
            accp.y = fmaf(A4.y,  W4.y + Wn4.y, accp.y);
            accm.y = fmaf(An4.y, W4.y - Wn4.y, accm.y);
            accp.z = fmaf(A4.z,  W4.z + Wn4.z, accp.z);
            accm.z = fmaf(An4.z, W4.z - Wn4.z, accm.z);
            accp.w = fmaf(A4.w,  W4.w + Wn4.w, accp.w);
            accm.w = fmaf(An4.w, W4.w - Wn4.w, accm.w);
        }
        float4 od;
        od.x = 0.5f * (accp.x + accm.x);
        od.y = 0.5f * (accp.y + accm.y);
        od.z = 0.5f * (accp.z + accm.z);
        od.w = 0.5f * (accp.w + accm.w);
        *(float4*)&odS[c * 256 + pix] = od;
    } else {
        // ---- waves 2-3: stage cas slices concurrently ----
        const int tt = t - 128;               // 0..127
        #pragma unroll
        for (int k = 0; k < 32; ++k) {
            int idx = tt + k * 128;           // 0..4095
            int s = idx >> 5, j = idx & 31;
            int f = (j < 16) ? j : (96 + j);
            casF[s * 33 + j] = cas[s * 128 + f];
        }
        #pragma unroll
        for (int k = 0; k < 16; ++k) {
            int idx = tt + k * 128;           // 0..2047
            casG[idx] = cas[idx];
        }
    }
    __syncthreads();

    // ---- R phase: R[s1,g] = sum_j casF[s1,j] odS[j,g] ----
    {
        const int s1 = t >> 1, gb = (t & 1) * 8;
        float acc[8];
        #pragma unroll
        for (int l = 0; l < 8; ++l) acc[l] = 0.f;
        #pragma unroll 4
        for (int j = 0; j < 32; ++j) {
            float cf = casF[s1 * 33 + j];
            #pragma unroll
            for (int l = 0; l < 8; ++l)
                acc[l] = fmaf(cf, odS[j * 16 + gb + l], acc[l]);
        }
        #pragma unroll
        for (int l = 0; l < 8; ++l) Rs[s1 * 17 + gb + l] = acc[l];
    }
    __syncthreads();   // all preloads complete before any in-place overwrite

    const float inv = 1.0f / 16384.0f;
    #pragma unroll
    for (int r = 0; r < 16; ++r) {        // FULL unroll: phv[r] static -> VGPR
        const int s1 = grp * 16 + r;
        float4 acc = {0.f, 0.f, 0.f, 0.f};
        #pragma unroll
        for (int g = 0; g < 16; ++g) {
            float rv = Rs[s1 * 17 + g];
            float4 c4 = *(const float4*)&casG[g * 128 + s2];
            acc.x = fmaf(rv, c4.x, acc.x);
            acc.y = fmaf(rv, c4.y, acc.y);
            acc.z = fmaf(rv, c4.z, acc.z);
            acc.w = fmaf(rv, c4.w, acc.w);
        }
        size_t idx = (size_t)img * 16384 + (size_t)s1 * 128 + s2;
        float4 res;
        res.x = acc.x * inv * (float)phv[r][0];
        res.y = acc.y * inv * (float)phv[r][1];
        res.z = acc.z * inv * (float)phv[r][2];
        res.w = acc.w * inv * (float)phv[r][3];
        *(float4*)&out[idx] = res;
    }
}

// ---------------------------------------------------------------------------
extern "C" void kernel_launch(void* const* d_in, const int* in_sizes, int n_in,
                              void* d_out, int out_size, void* d_ws, size_t ws_size,
                              hipStream_t stream) {
    (void)in_sizes; (void)n_in; (void)out_size; (void)ws_size;
    const float* x  = (const float*)d_in[0];
    const float* w1 = (const float*)d_in[1];
    const float* w2 = (const float*)d_in[2];
    float* out = (float*)d_out;
    float* ws  = (float*)d_ws;

    float* casf = ws;                        // 16384 f32
    f16* FAh = (f16*)(ws + 16384);           // 16384 halfs each, frag-ordered
    f16* FAl = FAh + 16384;
    f16* FVh = FAl + 16384;
    f16* FVl = FVh + 16384;
    float* cp1  = (float*)(FVl + 16384);     // 262144 f32 each
    float* cp2  = cp1 + 262144;
    float* cp1n = cp2 + 262144;
    float* cp2n = cp1n + 262144;             // total ~4.4 MB

    k_cas<<<dim3(128), dim3(128), 0, stream>>>(casf, FAh, FAl, FVh, FVl);
    k_dht<<<dim3(1024, 2), dim3(512), 0, stream>>>(x, FAh, FAl, FVh, FVl, out,
                                                   cp1, cp2, cp1n, cp2n);
    k_inv<<<dim3(1024), dim3(256), 0, stream>>>(cp1, cp2, cp1n, cp2n, w1, w2, casf, out);
}

// Round 17
// 155.112 us; speedup vs baseline: 1.0581x; 1.0581x over previous
//
#include <hip/hip_runtime.h>

typedef _Float16 f16;
typedef f16 f16x4 __attribute__((ext_vector_type(4)));
typedef f16 f16x8 __attribute__((ext_vector_type(8)));
typedef float f32x4 __attribute__((ext_vector_type(4)));

#define LSCALE 2048.0f          // lo-parts stored *2^11 (exact) to avoid f16 denormals
#define LINV   4.8828125e-4f    // 2^-11
#define XSX 136                 // X planes stride (halfs): b128-aligned rows
#define XSW 140                 // W planes stride (halfs): conflict-free scalar writes + b64 reads

#define MFMA(A,B,C) __builtin_amdgcn_mfma_f32_16x16x32_f16(A, B, C, 0, 0, 0)

// ---------------------------------------------------------------------------
// Kernel 0: replicate the reference's fp32 cas table EXACTLY (round-2 lesson:
// a more accurate table FAILS), then write split-f16 tables A=cas and
// V[f][m]=cas[f][127-m] in MFMA-FRAGMENT ORDER (round-10 lesson).
// ---------------------------------------------------------------------------
__device__ __forceinline__ int frag_slot(int row, int k) {
    return ((((row >> 4) * 4 + (k >> 5)) * 64) + ((k >> 3) & 3) * 16 + (row & 15)) * 8 + (k & 7);
}

__global__ void k_cas(float* __restrict__ casf,
                      f16* __restrict__ FAh, f16* __restrict__ FAl,
                      f16* __restrict__ FVh, f16* __restrict__ FVl) {
    int f = blockIdx.x, m = threadIdx.x;
    const float SC = (float)(6.283185307179586 / 128.0);  // fp32(2*pi/128)
    float ang = SC * (float)(f * m);                      // fp32, unreduced
    double a = (double)ang;
    float v = (float)cos(a) + (float)sin(a);
    casf[f * 128 + m] = v;
    f16 h = (f16)v;
    f16 lo = (f16)((v - (float)h) * LSCALE);
    int sA = frag_slot(f, m);
    FAh[sA] = h;
    FAl[sA] = lo;
    int sV = frag_slot(f, 127 - m);    // V[f][127-m] = cas[f][m]
    FVh[sV] = h;
    FVl[sV] = lo;
}

// ---------------------------------------------------------------------------
// Kernel 1: g-half split (grid 1024x2) with 1024-THREAD blocks: 71.7KB LDS ->
// 2 blocks/CU x 16 waves = 32 waves/CU = 8 waves/SIMD — DOUBLE every prior
// config (r8/r11/r15 were all 4/SIMD; pipe accounting showed serial phases).
// Wave tiles: pass1 32g x 16m (gq=wv&1, mq=wv>>1); pass2 16f x 32g
// (fq=wv>>1, gq2=wv&1). Per-element MFMA chain order identical to rounds
// 8-16 -> bitwise-identical C/S. __launch_bounds__(1024,8) caps VGPR at 64;
// table frags loaded per-gt to keep live set ~60.
// ---------------------------------------------------------------------------
__global__ __launch_bounds__(1024, 8) void k_dht(
    const float* __restrict__ xg,
    const f16* __restrict__ FAh, const f16* __restrict__ FAl,
    const f16* __restrict__ FVh, const f16* __restrict__ FVl,
    float* __restrict__ outbuf,
    float* __restrict__ cp1, float* __restrict__ cp2)
{
    __shared__ __align__(16) char smem[71680];
    f16* Xh  = (f16*)smem;               // [128][XSX] = 34816 B
    f16* Xl  = (f16*)(smem + 34816);     // ends 69632
    f16* W1h = (f16*)smem;               // [64][XSW] = 17920 B each, overlay X after pass 1
    f16* W1l = (f16*)(smem + 17920);
    f16* W2h = (f16*)(smem + 35840);
    f16* W2l = (f16*)(smem + 53760);     // ends 71680

    const int img = blockIdx.x;
    const int gh  = blockIdx.y;          // g-half: 0 or 1
    const float* X = xg + (size_t)img * 16384;
    const int t = threadIdx.x;           // 0..1023
    const int lane = t & 63;
    const int wv = t >> 6;               // 0..15
    const int l15 = lane & 15;
    const int a4 = lane >> 4;            // 0..3

    // ---- stage X -> split fp16 planes in LDS (b64 vector writes) ----
    #pragma unroll
    for (int it = 0; it < 4; ++it) {
        int i = it * 1024 + t;           // float4 index 0..4095
        int r = i >> 5, c0 = (i & 31) * 4;
        float4 xv = *(const float4*)&X[r * 128 + c0];
        const float* xp = (const float*)&xv;
        f16x4 hv, lv;
        #pragma unroll
        for (int j = 0; j < 4; ++j) {
            f16 h = (f16)xp[j];
            hv[j] = h;
            lv[j] = (f16)((xp[j] - (float)h) * LSCALE);
        }
        *(f16x4*)&Xh[r * XSX + c0] = hv;
        *(f16x4*)&Xl[r * XSX + c0] = lv;
    }
    __syncthreads();

    // ---- pass 1: wave tile (g local [32gq,+32), m [16mq,+16)) ----
    const int gq = wv & 1, mq = wv >> 1;     // gq 0..1, mq 0..7
    const int Gq = 2 * gh + gq;              // global 32-row g-tile 0..3
    f32x4 w1hi[2], w1lo[2], w2hi[2], w2lo[2];
    #pragma unroll
    for (int i = 0; i < 2; ++i) {
        w1hi[i] = (f32x4){0.f,0.f,0.f,0.f}; w1lo[i] = (f32x4){0.f,0.f,0.f,0.f};
        w2hi[i] = (f32x4){0.f,0.f,0.f,0.f}; w2lo[i] = (f32x4){0.f,0.f,0.f,0.f};
    }
    {
        #pragma unroll 1
        for (int ks = 0; ks < 4; ++ks) {
            const int base = (16 * mq + l15) * XSX + ks * 32 + 8 * a4;
            f16x8 xh = *(const f16x8*)&Xh[base];            // aligned b128
            f16x8 xl = *(const f16x8*)&Xl[base];
            #pragma unroll
            for (int gt = 0; gt < 2; ++gt) {
                const int toff = (((2 * Gq + gt) * 4 + ks) * 64 + lane) * 8;
                f16x8 tah = *(const f16x8*)&FAh[toff];
                f16x8 tal = *(const f16x8*)&FAl[toff];
                f16x8 tvh = *(const f16x8*)&FVh[toff];
                f16x8 tvl = *(const f16x8*)&FVl[toff];
                w1hi[gt] = MFMA(tah, xh, w1hi[gt]);
                w1lo[gt] = MFMA(tal, xh, w1lo[gt]);
                w1lo[gt] = MFMA(tah, xl, w1lo[gt]);
                w2hi[gt] = MFMA(tvh, xh, w2hi[gt]);
                w2lo[gt] = MFMA(tvl, xh, w2lo[gt]);
                w2lo[gt] = MFMA(tvh, xl, w2lo[gt]);
            }
        }
    }
    __syncthreads();   // X reads done before W overwrites the X region

    // ---- combine + split W into f16 h/l planes (local g rows 0..63) ----
    {
        const int m = 16 * mq + l15;
        #pragma unroll
        for (int gt = 0; gt < 2; ++gt) {
            #pragma unroll
            for (int r = 0; r < 4; ++r) {
                const int g = 32 * gq + 16 * gt + 4 * a4 + r;   // local
                float v1 = w1hi[gt][r] + LINV * w1lo[gt][r];
                f16 h1 = (f16)v1;
                float v2 = w2hi[gt][r] + LINV * w2lo[gt][r];
                f16 h2 = (f16)v2;
                W2h[g * XSW + m] = h2;
                W2l[g * XSW + m] = (f16)((v2 - (float)h2) * LSCALE);
                W1h[g * XSW + m] = h1;
                W1l[g * XSW + m] = (f16)((v1 - (float)h1) * LSCALE);
            }
        }
    }
    __syncthreads();

    // ---- pass 2: wave tile (f [16fq,+16), g local [32gq2,+32)) ----
    const int fq = wv >> 1, gq2 = wv & 1;    // fq 0..7, gq2 0..1
    f32x4 chi[2], clo[2], shi[2], slo[2];
    #pragma unroll
    for (int i = 0; i < 2; ++i) {
        chi[i] = (f32x4){0.f,0.f,0.f,0.f}; clo[i] = (f32x4){0.f,0.f,0.f,0.f};
        shi[i] = (f32x4){0.f,0.f,0.f,0.f}; slo[i] = (f32x4){0.f,0.f,0.f,0.f};
    }
    {
        #pragma unroll 1
        for (int ks = 0; ks < 4; ++ks) {
            const int toff = ((fq * 4 + ks) * 64 + lane) * 8;   // coalesced frag
            f16x8 tah = *(const f16x8*)&FAh[toff];
            f16x8 tal = *(const f16x8*)&FAl[toff];
            f16x8 tvh = *(const f16x8*)&FVh[toff];
            f16x8 tvl = *(const f16x8*)&FVl[toff];
            #pragma unroll
            for (int gt = 0; gt < 2; ++gt) {
                const int wb = (32 * gq2 + 16 * gt + l15) * XSW + ks * 32 + 8 * a4;
                f16x4 a0 = *(const f16x4*)&W1h[wb];
                f16x4 a1 = *(const f16x4*)&W1h[wb + 4];
                f16x4 b0 = *(const f16x4*)&W1l[wb];
                f16x4 b1 = *(const f16x4*)&W1l[wb + 4];
                f16x4 c0 = *(const f16x4*)&W2h[wb];
                f16x4 c1 = *(const f16x4*)&W2h[wb + 4];
                f16x4 d0 = *(const f16x4*)&W2l[wb];
                f16x4 d1 = *(const f16x4*)&W2l[wb + 4];
                f16x8 u1h = __builtin_shufflevector(a0, a1, 0,1,2,3,4,5,6,7);
                f16x8 u1l = __builtin_shufflevector(b0, b1, 0,1,2,3,4,5,6,7);
                f16x8 u2h = __builtin_shufflevector(c0, c1, 0,1,2,3,4,5,6,7);
                f16x8 u2l = __builtin_shufflevector(d0, d1, 0,1,2,3,4,5,6,7);
                chi[gt] = MFMA(tah, u1h, chi[gt]);
                clo[gt] = MFMA(tal, u1h, clo[gt]);
                clo[gt] = MFMA(tah, u1l, clo[gt]);
                shi[gt] = MFMA(tvh, u2h, shi[gt]);
                slo[gt] = MFMA(tvl, u2h, slo[gt]);
                slo[gt] = MFMA(tvh, u2l, slo[gt]);
            }
        }
    }

    // ---- epilogue: cosphi (f16, packed into out) + corners, in-register ----
    f16* cph = (f16*)(outbuf + (size_t)img * 16384);
    #pragma unroll
    for (int gt = 0; gt < 2; ++gt) {
        const int g = 64 * gh + 32 * gq2 + 16 * gt + l15;    // global g
        #pragma unroll
        for (int r = 0; r < 4; ++r) {
            const int f = 16 * fq + 4 * a4 + r;
            float Cv = chi[gt][r] + LINV * clo[gt][r];
            float Sv = shi[gt][r] + LINV * slo[gt][r];
            float d = Cv * Cv + Sv * Sv;
            float cp = (d > 0.f) ? Cv * rsqrtf(d) : 1.0f;
            cph[f * 128 + g] = (f16)cp;
            if (gh == 0 && gq2 == 0 && gt == 0) {    // g = l15 in 0..15
                if (fq == 0)                         // f in 0..15
                    cp1[img * 256 + f * 16 + l15] = Cv;
                else if (fq == 7)                    // f in 112..127
                    cp2[img * 256 + (f - 112) * 16 + l15] = Cv;
            }
        }
    }
}

// ---------------------------------------------------------------------------
// Kernel 2: EXACT round-11 fused k_inv (best measured tail ~55us; the r13
// register-preload, r14 512-thr split, r15 dual-chain, and r16 float4-corner
// variants all measured WORSE — reverted).
// ---------------------------------------------------------------------------
__global__ __launch_bounds__(256) void k_inv(
    const float* __restrict__ cp1, const float* __restrict__ cp2,
    const float* __restrict__ w1,  const float* __restrict__ w2,
    const float* __restrict__ cas,
    float* __restrict__ out)
{
    __shared__ float odS[32 * 16];
    __shared__ float casF[128 * 33];
    __shared__ float Rs[128 * 17];
    __shared__ float casG[16 * 128];
    __shared__ __align__(16) unsigned short cphS[16384];   // 32KB

    const int img = blockIdx.x;
    const int b = img >> 6, o = img & 63;
    const int t = threadIdx.x;

    // stage f16 cosphi (in-place region of out)
    const uint4* cp16 = (const uint4*)(out + (size_t)img * 16384);
    #pragma unroll
    for (int k = 0; k < 8; ++k) {
        int i = k * 256 + t;
        ((uint4*)cphS)[i] = cp16[i];
    }

    // ---- corner phase (both corners, in-register) ----
    {
        const int xx = t >> 4, yy = t & 15;
        const int nx = (16 - xx) & 15, ny = (16 - yy) & 15;
        const int pf = xx * 16 + yy, pn = nx * 16 + ny;
        float acc1 = 0.f, acc2 = 0.f;
        #pragma unroll 4
        for (int i = 0; i < 64; ++i) {
            const int cb = (b * 64 + i) * 256;
            const int wb = (i * 64 + o) * 256;
            float A1  = cp1[cb + pf];
            float A1n = cp1[cb + pn];
            float W1v = w1[wb + pf];
            float W1n = w1[wb + pn];
            acc1 += A1 * (W1v + W1n) + A1n * (W1v - W1n);
            float A2  = cp2[cb + pf];
            float A2n = cp2[cb + pn];
            float W2v = w2[wb + pf];
            float W2n = w2[wb + pn];
            acc2 += A2 * (W2v + W2n) + A2n * (W2v - W2n);
        }
        odS[pf]       = 0.5f * acc1;
        odS[256 + pf] = 0.5f * acc2;
    }

    // ---- stage cas slices ----
    #pragma unroll
    for (int k = 0; k < 16; ++k) {
        int idx = t + k * 256;
        int s = idx >> 5, j = idx & 31;
        int f = (j < 16) ? j : (96 + j);
        casF[s * 33 + j] = cas[s * 128 + f];
    }
    #pragma unroll
    for (int k = 0; k < 8; ++k) {
        int idx = t + k * 256;
        casG[idx] = cas[idx];
    }
    __syncthreads();

    {
        const int s1 = t >> 1, gb = (t & 1) * 8;
        float acc[8];
        #pragma unroll
        for (int l = 0; l < 8; ++l) acc[l] = 0.f;
        #pragma unroll 4
        for (int j = 0; j < 32; ++j) {
            float cf = casF[s1 * 33 + j];
            #pragma unroll
            for (int l = 0; l < 8; ++l)
                acc[l] = fmaf(cf, odS[j * 16 + gb + l], acc[l]);
        }
        #pragma unroll
        for (int l = 0; l < 8; ++l) Rs[s1 * 17 + gb + l] = acc[l];
    }
    __syncthreads();

    const float inv = 1.0f / 16384.0f;
    const int grp = t >> 5, lane = t & 31;
    const int s2 = lane * 4;
    for (int r = 0; r < 16; ++r) {
        const int s1 = grp * 16 + r;
        float4 acc = {0.f, 0.f, 0.f, 0.f};
        #pragma unroll
        for (int g = 0; g < 16; ++g) {
            float rv = Rs[s1 * 17 + g];
            float4 c4 = *(const float4*)&casG[g * 128 + s2];
            acc.x = fmaf(rv, c4.x, acc.x);
            acc.y = fmaf(rv, c4.y, acc.y);
            acc.z = fmaf(rv, c4.z, acc.z);
            acc.w = fmaf(rv, c4.w, acc.w);
        }
        const f16* ph = (const f16*)cphS + s1 * 128 + s2;
        size_t idx = (size_t)img * 16384 + (size_t)s1 * 128 + s2;
        float4 res;
        res.x = acc.x * inv * (float)ph[0];
        res.y = acc.y * inv * (float)ph[1];
        res.z = acc.z * inv * (float)ph[2];
        res.w = acc.w * inv * (float)ph[3];
        *(float4*)&out[idx] = res;
    }
}

// ---------------------------------------------------------------------------
extern "C" void kernel_launch(void* const* d_in, const int* in_sizes, int n_in,
                              void* d_out, int out_size, void* d_ws, size_t ws_size,
                              hipStream_t stream) {
    (void)in_sizes; (void)n_in; (void)out_size; (void)ws_size;
    const float* x  = (const float*)d_in[0];
    const float* w1 = (const float*)d_in[1];
    const float* w2 = (const float*)d_in[2];
    float* out = (float*)d_out;
    float* ws  = (float*)d_ws;

    float* casf = ws;                        // 16384 f32
    f16* FAh = (f16*)(ws + 16384);           // 16384 halfs each, frag-ordered
    f16* FAl = FAh + 16384;
    f16* FVh = FAl + 16384;
    f16* FVl = FVh + 16384;
    float* cp1 = (float*)(FVl + 16384);      // 262144 f32 each
    float* cp2 = cp1 + 262144;               // total ~2.3 MB

    k_cas<<<dim3(128), dim3(128), 0, stream>>>(casf, FAh, FAl, FVh, FVl);
    k_dht<<<dim3(1024, 2), dim3(1024), 0, stream>>>(x, FAh, FAl, FVh, FVl, out, cp1, cp2);
    k_inv<<<dim3(1024), dim3(256), 0, stream>>>(cp1, cp2, w1, w2, casf, out);
}

// Round 18
// 140.315 us; speedup vs baseline: 1.1697x; 1.1055x over previous
//
#include <hip/hip_runtime.h>

typedef _Float16 f16;
typedef f16 f16x4 __attribute__((ext_vector_type(4)));
typedef f16 f16x8 __attribute__((ext_vector_type(8)));
typedef float f32x4 __attribute__((ext_vector_type(4)));

#define LSCALE 2048.0f          // lo-parts stored *2^11 (exact) to avoid f16 denormals
#define LINV   4.8828125e-4f    // 2^-11
#define XSX 136                 // X planes stride (halfs): b128-aligned rows, conflict-free reads
#define XSW 140                 // W planes stride (halfs): rows+4k -> banks {0,24,16,8} (conflict fix)

#define MFMA(A,B,C) __builtin_amdgcn_mfma_f32_16x16x32_f16(A, B, C, 0, 0, 0)

// ---------------------------------------------------------------------------
// Kernel 0: replicate the reference's fp32 cas table EXACTLY (round-2 lesson:
// a more accurate table FAILS), then write split-f16 tables A=cas and
// V[f][m]=cas[f][127-m] in MFMA-FRAGMENT ORDER (round-10 lesson: row-major
// fragment loads are 32-line gathers; frag order -> one coalesced transaction).
// ---------------------------------------------------------------------------
__device__ __forceinline__ int frag_slot(int row, int k) {
    return ((((row >> 4) * 4 + (k >> 5)) * 64) + ((k >> 3) & 3) * 16 + (row & 15)) * 8 + (k & 7);
}

__global__ void k_cas(float* __restrict__ casf,
                      f16* __restrict__ FAh, f16* __restrict__ FAl,
                      f16* __restrict__ FVh, f16* __restrict__ FVl) {
    int f = blockIdx.x, m = threadIdx.x;
    const float SC = (float)(6.283185307179586 / 128.0);  // fp32(2*pi/128)
    float ang = SC * (float)(f * m);                      // fp32, unreduced
    double a = (double)ang;
    float v = (float)cos(a) + (float)sin(a);
    casf[f * 128 + m] = v;
    f16 h = (f16)v;
    f16 lo = (f16)((v - (float)h) * LSCALE);
    int sA = frag_slot(f, m);
    FAh[sA] = h;
    FAl[sA] = lo;
    int sV = frag_slot(f, 127 - m);    // V[f][127-m] = cas[f][m]
    FVh[sV] = h;
    FVl[sV] = lo;
}

// ---------------------------------------------------------------------------
// Kernel 1: ROUND-11 structure (best measured: 80.8us; the r12 32x32-tile,
// r15 g-half-split, r17 8-wave variants all measured equal or worse).
// 16 waves, one image/block. Only change vs r11: W planes at stride 140
// (banks {0,24,16,8} for the 4 a4-groups' combine writes -> conflicts
// 6.3M->~1M, value-identical).
//   pass1: wave (gw=wv&7, mh=(wv>>3)*4): W1[g,m]=sum_n A[g,n]X[m,n], W2 from V
//   pass2: wave (ft=wv>>1, gh=wv&1): C[f,g]=sum_m A[f,m]W1[g,m],
//          S[f,g]=sum_m V[f,m]W2[g,m] -> in-register cosphi pairing.
// Split-fp16: P*Q = Ph*Qh + 2^-11*(Pl'*Qh + Ph*Ql').  Same MFMA chain order
// since round 8 -> bitwise-identical output (absmax 3.814697e-06).
// ---------------------------------------------------------------------------
__global__ __launch_bounds__(1024) void k_dht(
    const float* __restrict__ xg,
    const f16* __restrict__ FAh, const f16* __restrict__ FAl,
    const f16* __restrict__ FVh, const f16* __restrict__ FVl,
    float* __restrict__ outbuf,
    float* __restrict__ cp1, float* __restrict__ cp2)
{
    __shared__ __align__(16) char smem[143360];
    f16* Xh  = (f16*)smem;               // [128][XSX] = 34816 B
    f16* Xl  = (f16*)(smem + 35840);
    f16* W1h = (f16*)smem;               // [128][XSW] = 35840 B each, overlay X after pass 1
    f16* W1l = (f16*)(smem + 35840);
    f16* W2h = (f16*)(smem + 71680);
    f16* W2l = (f16*)(smem + 107520);

    const int img = blockIdx.x;
    const float* X = xg + (size_t)img * 16384;
    const int t = threadIdx.x;
    const int lane = t & 63;
    const int wv = t >> 6;               // 0..15
    const int l15 = lane & 15;
    const int a4 = lane >> 4;            // 0..3

    // ---- stage X -> split fp16 planes in LDS (b64 vector writes) ----
    #pragma unroll
    for (int it = 0; it < 4; ++it) {
        int i = it * 1024 + t;           // float4 index 0..4095
        int r = i >> 5, c0 = (i & 31) * 4;
        float4 xv = *(const float4*)&X[r * 128 + c0];
        const float* xp = (const float*)&xv;
        f16x4 hv, lv;
        #pragma unroll
        for (int j = 0; j < 4; ++j) {
            f16 h = (f16)xp[j];
            hv[j] = h;
            lv[j] = (f16)((xp[j] - (float)h) * LSCALE);
        }
        *(f16x4*)&Xh[r * XSX + c0] = hv;
        *(f16x4*)&Xl[r * XSX + c0] = lv;
    }
    __syncthreads();

    // ---- pass 1: wave -> (gtile gw, m-half mh), computes W1 and W2 tiles ----
    const int gw = wv & 7;
    const int mh = (wv >> 3) * 4;
    f32x4 w1hi[4], w1lo[4], w2hi[4], w2lo[4];
    #pragma unroll
    for (int i = 0; i < 4; ++i) {
        w1hi[i] = (f32x4){0.f,0.f,0.f,0.f}; w1lo[i] = (f32x4){0.f,0.f,0.f,0.f};
        w2hi[i] = (f32x4){0.f,0.f,0.f,0.f}; w2lo[i] = (f32x4){0.f,0.f,0.f,0.f};
    }
    {
        #pragma unroll 1
        for (int ks = 0; ks < 4; ++ks) {
            const int toff = ((gw * 4 + ks) * 64 + lane) * 8;   // coalesced frag
            f16x8 tah = *(const f16x8*)&FAh[toff];
            f16x8 tal = *(const f16x8*)&FAl[toff];
            f16x8 tvh = *(const f16x8*)&FVh[toff];
            f16x8 tvl = *(const f16x8*)&FVl[toff];
            #pragma unroll
            for (int mi = 0; mi < 4; ++mi) {
                const int base = (16 * (mh + mi) + l15) * XSX + ks * 32 + 8 * a4;
                f16x8 xh = *(const f16x8*)&Xh[base];            // aligned b128
                f16x8 xl = *(const f16x8*)&Xl[base];
                w1hi[mi] = MFMA(tah, xh, w1hi[mi]);
                w1lo[mi] = MFMA(tal, xh, w1lo[mi]);
                w1lo[mi] = MFMA(tah, xl, w1lo[mi]);
                w2hi[mi] = MFMA(tvh, xh, w2hi[mi]);
                w2lo[mi] = MFMA(tvl, xh, w2lo[mi]);
                w2lo[mi] = MFMA(tvh, xl, w2lo[mi]);
            }
        }
    }
    __syncthreads();

    // ---- combine + split W into f16 h/l planes (W1 over X region) ----
    {
        const int g = 16 * gw + 4 * a4;
        #pragma unroll
        for (int mi = 0; mi < 4; ++mi) {
            const int m = 16 * (mh + mi) + l15;
            #pragma unroll
            for (int r = 0; r < 4; ++r) {
                float v1 = w1hi[mi][r] + LINV * w1lo[mi][r];
                f16 h1 = (f16)v1;
                float v2 = w2hi[mi][r] + LINV * w2lo[mi][r];
                f16 h2 = (f16)v2;
                W2h[(g + r) * XSW + m] = h2;
                W2l[(g + r) * XSW + m] = (f16)((v2 - (float)h2) * LSCALE);
                W1h[(g + r) * XSW + m] = h1;
                W1l[(g + r) * XSW + m] = (f16)((v1 - (float)h1) * LSCALE);
            }
        }
    }
    __syncthreads();

    // ---- pass 2: wave (ft = wv>>1, ghalf = wv&1): C and S paired ----
    const int ft = wv >> 1;
    const int gh = wv & 1;
    f32x4 chi[4], clo[4], shi[4], slo[4];
    #pragma unroll
    for (int i = 0; i < 4; ++i) {
        chi[i] = (f32x4){0.f,0.f,0.f,0.f}; clo[i] = (f32x4){0.f,0.f,0.f,0.f};
        shi[i] = (f32x4){0.f,0.f,0.f,0.f}; slo[i] = (f32x4){0.f,0.f,0.f,0.f};
    }
    {
        #pragma unroll 1
        for (int ks = 0; ks < 4; ++ks) {
            const int toff = ((ft * 4 + ks) * 64 + lane) * 8;   // coalesced frag
            f16x8 tah = *(const f16x8*)&FAh[toff];
            f16x8 tal = *(const f16x8*)&FAl[toff];
            f16x8 tvh = *(const f16x8*)&FVh[toff];
            f16x8 tvl = *(const f16x8*)&FVl[toff];
            #pragma unroll
            for (int gi = 0; gi < 4; ++gi) {
                const int gt = 4 * gh + gi;
                const int wb = (16 * gt + l15) * XSW + ks * 32 + 8 * a4;
                f16x4 a0 = *(const f16x4*)&W1h[wb];
                f16x4 a1 = *(const f16x4*)&W1h[wb + 4];
                f16x4 b0 = *(const f16x4*)&W1l[wb];
                f16x4 b1 = *(const f16x4*)&W1l[wb + 4];
                f16x4 c0 = *(const f16x4*)&W2h[wb];
                f16x4 c1 = *(const f16x4*)&W2h[wb + 4];
                f16x4 d0 = *(const f16x4*)&W2l[wb];
                f16x4 d1 = *(const f16x4*)&W2l[wb + 4];
                f16x8 u1h = __builtin_shufflevector(a0, a1, 0,1,2,3,4,5,6,7);
                f16x8 u1l = __builtin_shufflevector(b0, b1, 0,1,2,3,4,5,6,7);
                f16x8 u2h = __builtin_shufflevector(c0, c1, 0,1,2,3,4,5,6,7);
                f16x8 u2l = __builtin_shufflevector(d0, d1, 0,1,2,3,4,5,6,7);
                chi[gi] = MFMA(tah, u1h, chi[gi]);
                clo[gi] = MFMA(tal, u1h, clo[gi]);
                clo[gi] = MFMA(tah, u1l, clo[gi]);
                shi[gi] = MFMA(tvh, u2h, shi[gi]);
                slo[gi] = MFMA(tvl, u2h, slo[gi]);
                slo[gi] = MFMA(tvh, u2l, slo[gi]);
            }
        }
    }

    // ---- epilogue: cosphi (f16, packed into out) + corners, in-register ----
    f16* cph = (f16*)(outbuf + (size_t)img * 16384);
    #pragma unroll
    for (int gi = 0; gi < 4; ++gi) {
        const int g = 16 * (4 * gh + gi) + l15;
        #pragma unroll
        for (int r = 0; r < 4; ++r) {
            const int f = 16 * ft + 4 * a4 + r;
            float Cv = chi[gi][r] + LINV * clo[gi][r];
            float Sv = shi[gi][r] + LINV * slo[gi][r];
            float d = Cv * Cv + Sv * Sv;
            float cp = (d > 0.f) ? Cv * rsqrtf(d) : 1.0f;
            cph[f * 128 + g] = (f16)cp;
            if (gh == 0 && gi == 0) {
                if (ft == 0)      cp1[img * 256 + f * 16 + l15] = Cv;
                else if (ft == 7) cp2[img * 256 + (f - 112) * 16 + l15] = Cv;
            }
        }
    }
}

// ---------------------------------------------------------------------------
// Kernel 2: EXACT round-11 fused k_inv (best measured tail; r13 register-
// preload, r14 512-thr split, r15 dual-chain, r16 float4-corner all WORSE).
// corner -> odS (LDS); R = casF*od; out = (R*casG/16384)*cosphi, with cosphi
// f16-packed in out's first 32KB per image, staged via LDS (in-place safe).
// ---------------------------------------------------------------------------
__global__ __launch_bounds__(256) void k_inv(
    const float* __restrict__ cp1, const float* __restrict__ cp2,
    const float* __restrict__ w1,  const float* __restrict__ w2,
    const float* __restrict__ cas,
    float* __restrict__ out)
{
    __shared__ float odS[32 * 16];
    __shared__ float casF[128 * 33];
    __shared__ float Rs[128 * 17];
    __shared__ float casG[16 * 128];
    __shared__ __align__(16) unsigned short cphS[16384];   // 32KB

    const int img = blockIdx.x;
    const int b = img >> 6, o = img & 63;
    const int t = threadIdx.x;

    // stage f16 cosphi (in-place region of out)
    const uint4* cp16 = (const uint4*)(out + (size_t)img * 16384);
    #pragma unroll
    for (int k = 0; k < 8; ++k) {
        int i = k * 256 + t;
        ((uint4*)cphS)[i] = cp16[i];
    }

    // ---- corner phase (both corners, in-register) ----
    {
        const int xx = t >> 4, yy = t & 15;
        const int nx = (16 - xx) & 15, ny = (16 - yy) & 15;
        const int pf = xx * 16 + yy, pn = nx * 16 + ny;
        float acc1 = 0.f, acc2 = 0.f;
        #pragma unroll 4
        for (int i = 0; i < 64; ++i) {
            const int cb = (b * 64 + i) * 256;
            const int wb = (i * 64 + o) * 256;
            float A1  = cp1[cb + pf];
            float A1n = cp1[cb + pn];
            float W1v = w1[wb + pf];
            float W1n = w1[wb + pn];
            acc1 += A1 * (W1v + W1n) + A1n * (W1v - W1n);
            float A2  = cp2[cb + pf];
            float A2n = cp2[cb + pn];
            float W2v = w2[wb + pf];
            float W2n = w2[wb + pn];
            acc2 += A2 * (W2v + W2n) + A2n * (W2v - W2n);
        }
        odS[pf]       = 0.5f * acc1;
        odS[256 + pf] = 0.5f * acc2;
    }

    // ---- stage cas slices ----
    #pragma unroll
    for (int k = 0; k < 16; ++k) {
        int idx = t + k * 256;
        int s = idx >> 5, j = idx & 31;
        int f = (j < 16) ? j : (96 + j);
        casF[s * 33 + j] = cas[s * 128 + f];
    }
    #pragma unroll
    for (int k = 0; k < 8; ++k) {
        int idx = t + k * 256;
        casG[idx] = cas[idx];
    }
    __syncthreads();

    {
        const int s1 = t >> 1, gb = (t & 1) * 8;
        float acc[8];
        #pragma unroll
        for (int l = 0; l < 8; ++l) acc[l] = 0.f;
        #pragma unroll 4
        for (int j = 0; j < 32; ++j) {
            float cf = casF[s1 * 33 + j];
            #pragma unroll
            for (int l = 0; l < 8; ++l)
                acc[l] = fmaf(cf, odS[j * 16 + gb + l], acc[l]);
        }
        #pragma unroll
        for (int l = 0; l < 8; ++l) Rs[s1 * 17 + gb + l] = acc[l];
    }
    __syncthreads();

    const float inv = 1.0f / 16384.0f;
    const int grp = t >> 5, lane = t & 31;
    const int s2 = lane * 4;
    for (int r = 0; r < 16; ++r) {
        const int s1 = grp * 16 + r;
        float4 acc = {0.f, 0.f, 0.f, 0.f};
        #pragma unroll
        for (int g = 0; g < 16; ++g) {
            float rv = Rs[s1 * 17 + g];
            float4 c4 = *(const float4*)&casG[g * 128 + s2];
            acc.x = fmaf(rv, c4.x, acc.x);
            acc.y = fmaf(rv, c4.y, acc.y);
            acc.z = fmaf(rv, c4.z, acc.z);
            acc.w = fmaf(rv, c4.w, acc.w);
        }
        const f16* ph = (const f16*)cphS + s1 * 128 + s2;
        size_t idx = (size_t)img * 16384 + (size_t)s1 * 128 + s2;
        float4 res;
        res.x = acc.x * inv * (float)ph[0];
        res.y = acc.y * inv * (float)ph[1];
        res.z = acc.z * inv * (float)ph[2];
        res.w = acc.w * inv * (float)ph[3];
        *(float4*)&out[idx] = res;
    }
}

// ---------------------------------------------------------------------------
extern "C" void kernel_launch(void* const* d_in, const int* in_sizes, int n_in,
                              void* d_out, int out_size, void* d_ws, size_t ws_size,
                              hipStream_t stream) {
    (void)in_sizes; (void)n_in; (void)out_size; (void)ws_size;
    const float* x  = (const float*)d_in[0];
    const float* w1 = (const float*)d_in[1];
    const float* w2 = (const float*)d_in[2];
    float* out = (float*)d_out;
    float* ws  = (float*)d_ws;

    float* casf = ws;                        // 16384 f32
    f16* FAh = (f16*)(ws + 16384);           // 16384 halfs each, frag-ordered
    f16* FAl = FAh + 16384;
    f16* FVh = FAl + 16384;
    f16* FVl = FVh + 16384;
    float* cp1 = (float*)(FVl + 16384);      // 262144 f32 each
    float* cp2 = cp1 + 262144;               // total ~2.3 MB

    k_cas<<<dim3(128), dim3(128), 0, stream>>>(casf, FAh, FAl, FVh, FVl);
    k_dht<<<dim3(1024), dim3(1024), 0, stream>>>(x, FAh, FAl, FVh, FVl, out, cp1, cp2);
    k_inv<<<dim3(1024), dim3(256), 0, stream>>>(cp1, cp2, w1, w2, casf, out);
}